// Round 1
// baseline (353.637 us; speedup 1.0000x reference)
//
#include <hip/hip_runtime.h>
#include <hip/hip_cooperative_groups.h>
#include <math.h>

namespace cg = cooperative_groups;

#define EPS_COV 1e-6f
#define NBLOCKS 1024
#define NTHREADS 256

typedef float vfloat4 __attribute__((ext_vector_type(4)));  // nt-load-compatible

// ws layout: double partials[NBLOCKS] @ offset 0.

// ---- shared device helpers -------------------------------------------------

// Per-thread posterior params for row-quarter q: blocks n=2q and n=2q+1 ONLY
// (the old kernel computed all 8 and discarded 6 — 4x the divides/VALU).
// Arithmetic per block is expression-for-expression identical to before.
__device__ __forceinline__ void setup_params(
    const float* __restrict__ mu_like, const float* __restrict__ pose,
    const float* __restrict__ sp_prior, const float* __restrict__ sp_like, int q,
    float& m0, float& m1, float& m2, float& m3,
    float& a0, float& b0, float& c0,
    float& a1, float& b1, float& c1)
{
    float cx = 0.f, cy = 0.f;
    #pragma unroll
    for (int i = 0; i < 8; ++i) { cx += mu_like[2*i]; cy += mu_like[2*i+1]; }
    cx *= 0.125f; cy *= 0.125f;
    const float ct = cosf(pose[2]), st = sinf(pose[2]);
    const float tx = pose[0], ty = pose[1];

    #pragma unroll
    for (int k = 0; k < 2; ++k) {
        const int n = 2*q + k;
        float px = mu_like[2*n]   - cx;
        float py = mu_like[2*n+1] - cy;
        float mp0 = ct*px - st*py + tx;
        float mp1 = st*px + ct*py + ty;

        const float* p = sp_prior + 4*n;
        float s00 = p[0]*p[0] + p[1]*p[1] + EPS_COV;
        float s01 = p[0]*p[2] + p[1]*p[3];
        float s11 = p[2]*p[2] + p[3]*p[3] + EPS_COV;
        float det = s00*s11 - s01*s01;
        float Pp00 =  s11/det, Pp01 = -s01/det, Pp11 = s00/det;

        const float* l = sp_like + 4*n;
        float t00 = l[0]*l[0] + l[1]*l[1] + EPS_COV;
        float t01 = l[0]*l[2] + l[1]*l[3];
        float t11 = l[2]*l[2] + l[3]*l[3] + EPS_COV;
        float dl = t00*t11 - t01*t01;
        float Pl00 =  t11/dl, Pl01 = -t01/dl, Pl11 = t00/dl;

        float Q00 = Pp00 + Pl00, Q01 = Pp01 + Pl01, Q11 = Pp11 + Pl11;
        float dq = Q00*Q11 - Q01*Q01;
        float S00 = Q11/dq, S01 = -Q01/dq, S11v = Q00/dq;

        float ml0 = mu_like[2*n], ml1 = mu_like[2*n+1];
        float v0 = Pp00*mp0 + Pp01*mp1 + Pl00*ml0 + Pl01*ml1;
        float v1 = Pp01*mp0 + Pp11*mp1 + Pl01*ml0 + Pl11*ml1;
        float mpostx = S00*v0 + S01*v1;
        float mposty = S01*v0 + S11v*v1;

        if (k == 0) { m0 = mpostx; m1 = mposty; a0 = S00; b0 = 2.f*S01; c0 = S11v; }
        else        { m2 = mpostx; m3 = mposty; a1 = S00; b1 = 2.f*S01; c1 = S11v; }
    }
}

__device__ __forceinline__ double logdet_posterior(
    const float* __restrict__ sp_prior, const float* __restrict__ sp_like)
{
    double logdet = 0.0;
    for (int n = 0; n < 8; ++n) {
        const float* p = sp_prior + 4*n;
        double s00 = (double)p[0]*p[0] + (double)p[1]*p[1] + 1e-6;
        double s01 = (double)p[0]*p[2] + (double)p[1]*p[3];
        double s11 = (double)p[2]*p[2] + (double)p[3]*p[3] + 1e-6;
        double det = s00*s11 - s01*s01;
        double Pp00 = s11/det, Pp01 = -s01/det, Pp11 = s00/det;
        const float* l = sp_like + 4*n;
        double t00 = (double)l[0]*l[0] + (double)l[1]*l[1] + 1e-6;
        double t01 = (double)l[0]*l[2] + (double)l[1]*l[3];
        double t11 = (double)l[2]*l[2] + (double)l[3]*l[3] + 1e-6;
        double dl = t00*t11 - t01*t01;
        double Pl00 = t11/dl, Pl01 = -t01/dl, Pl11 = t00/dl;
        double Q00 = Pp00 + Pl00, Q01 = Pp01 + Pl01, Q11 = Pp11 + Pl11;
        logdet += log(Q00*Q11 - Q01*Q01);
    }
    return logdet;
}

// ---- fused cooperative kernel ---------------------------------------------
// Stream quad-form -> block partial -> grid.sync() -> block 0 finalizes.
// Removes the 1-block finalize dispatch + its launch gap from the graph.

__global__ __launch_bounds__(NTHREADS, 4) void fused_quad_kernel(
    const vfloat4* __restrict__ obs4,
    const float*  __restrict__ mu_like,
    const float*  __restrict__ pose,
    const float*  __restrict__ sp_prior,
    const float*  __restrict__ sp_like,
    double*       __restrict__ partials,
    float*        __restrict__ out,
    int n4, double n_obs)
{
    const int tid    = blockIdx.x * blockDim.x + threadIdx.x;
    const int stride = gridDim.x * blockDim.x;   // multiple of 4 -> q loop-invariant
    const int q = tid & 3;

    float m0, m1, m2, m3, a0, b0, c0, a1, b1, c1;
    setup_params(mu_like, pose, sp_prior, sp_like, q,
                 m0, m1, m2, m3, a0, b0, c0, a1, b1, c1);

    // ---- streaming quad-form accumulation, NON-TEMPORAL loads ----
    float acc0 = 0.f, acc1 = 0.f;
    int i = tid;
    while (i + 7*stride < n4) {
        vfloat4 v[8];
        #pragma unroll
        for (int j = 0; j < 8; ++j)
            v[j] = __builtin_nontemporal_load(&obs4[i + j*stride]);
        #pragma unroll
        for (int j = 0; j < 8; ++j) {
            float d0 = v[j].x - m0, d1 = v[j].y - m1;
            float d2 = v[j].z - m2, d3 = v[j].w - m3;
            float t = a0*d0*d0 + b0*(d0*d1) + c0*d1*d1
                    + a1*d2*d2 + b1*(d2*d3) + c1*d3*d3;
            if (j & 1) acc1 += t; else acc0 += t;
        }
        i += 8*stride;
    }
    for (; i < n4; i += stride) {
        vfloat4 v = __builtin_nontemporal_load(&obs4[i]);
        float d0 = v.x - m0, d1 = v.y - m1;
        float d2 = v.z - m2, d3 = v.w - m3;
        acc0 += a0*d0*d0 + b0*(d0*d1) + c0*d1*d1
              + a1*d2*d2 + b1*(d2*d3) + c1*d3*d3;
    }

    double accd = (double)acc0 + (double)acc1;

    #pragma unroll
    for (int off = 32; off > 0; off >>= 1)
        accd += __shfl_down(accd, off, 64);

    __shared__ double lds[4];
    const int wave = threadIdx.x >> 6;
    if ((threadIdx.x & 63) == 0) lds[wave] = accd;
    __syncthreads();
    if (threadIdx.x == 0) {
        double blocksum = lds[0] + lds[1] + lds[2] + lds[3];
        // agent-scope release store: visible across XCDs after grid sync
        __hip_atomic_store(&partials[blockIdx.x], blocksum,
                           __ATOMIC_RELEASE, __HIP_MEMORY_SCOPE_AGENT);
    }

    cg::this_grid().sync();

    if (blockIdx.x == 0) {
        double s = 0.0;
        for (int k = threadIdx.x; k < NBLOCKS; k += NTHREADS)
            s += __hip_atomic_load(&partials[k], __ATOMIC_RELAXED,
                                   __HIP_MEMORY_SCOPE_AGENT);
        #pragma unroll
        for (int off = 32; off > 0; off >>= 1)
            s += __shfl_down(s, off, 64);
        __syncthreads();                     // lds[] reuse hazard
        if ((threadIdx.x & 63) == 0) lds[wave] = s;
        __syncthreads();
        if (threadIdx.x == 0) {
            double total = lds[0] + lds[1] + lds[2] + lds[3];
            const double LOG_2PI = 1.8378770664093454835606594728112;
            double c = n_obs * (16.0 * LOG_2PI + 0.5 * logdet_posterior(sp_prior, sp_like));
            out[0] = (float)(c + 0.5 * total);
        }
    }
}

// ---- fallback path (non-cooperative), in case coop launch fails in capture --

__global__ __launch_bounds__(NTHREADS) void quad_stream_kernel(
    const vfloat4* __restrict__ obs4,
    const float*  __restrict__ mu_like,
    const float*  __restrict__ pose,
    const float*  __restrict__ sp_prior,
    const float*  __restrict__ sp_like,
    double*       __restrict__ partials,
    int n4)
{
    const int tid    = blockIdx.x * blockDim.x + threadIdx.x;
    const int stride = gridDim.x * blockDim.x;
    const int q = tid & 3;

    float m0, m1, m2, m3, a0, b0, c0, a1, b1, c1;
    setup_params(mu_like, pose, sp_prior, sp_like, q,
                 m0, m1, m2, m3, a0, b0, c0, a1, b1, c1);

    float acc0 = 0.f, acc1 = 0.f;
    int i = tid;
    while (i + 7*stride < n4) {
        vfloat4 v[8];
        #pragma unroll
        for (int j = 0; j < 8; ++j)
            v[j] = __builtin_nontemporal_load(&obs4[i + j*stride]);
        #pragma unroll
        for (int j = 0; j < 8; ++j) {
            float d0 = v[j].x - m0, d1 = v[j].y - m1;
            float d2 = v[j].z - m2, d3 = v[j].w - m3;
            float t = a0*d0*d0 + b0*(d0*d1) + c0*d1*d1
                    + a1*d2*d2 + b1*(d2*d3) + c1*d3*d3;
            if (j & 1) acc1 += t; else acc0 += t;
        }
        i += 8*stride;
    }
    for (; i < n4; i += stride) {
        vfloat4 v = __builtin_nontemporal_load(&obs4[i]);
        float d0 = v.x - m0, d1 = v.y - m1;
        float d2 = v.z - m2, d3 = v.w - m3;
        acc0 += a0*d0*d0 + b0*(d0*d1) + c0*d1*d1
              + a1*d2*d2 + b1*(d2*d3) + c1*d3*d3;
    }

    double accd = (double)acc0 + (double)acc1;
    #pragma unroll
    for (int off = 32; off > 0; off >>= 1)
        accd += __shfl_down(accd, off, 64);

    __shared__ double lds[4];
    const int wave = threadIdx.x >> 6;
    if ((threadIdx.x & 63) == 0) lds[wave] = accd;
    __syncthreads();
    if (threadIdx.x == 0)
        partials[blockIdx.x] = lds[0] + lds[1] + lds[2] + lds[3];
}

__global__ __launch_bounds__(NTHREADS) void finalize_kernel(
    const double* __restrict__ partials,
    const float*  __restrict__ sp_prior,
    const float*  __restrict__ sp_like,
    float*        __restrict__ out,
    int nblocks, double n_obs)
{
    double s = 0.0;
    for (int i = threadIdx.x; i < nblocks; i += NTHREADS) s += partials[i];
    #pragma unroll
    for (int off = 32; off > 0; off >>= 1)
        s += __shfl_down(s, off, 64);
    __shared__ double lds[4];
    const int wave = threadIdx.x >> 6;
    if ((threadIdx.x & 63) == 0) lds[wave] = s;
    __syncthreads();

    if (threadIdx.x == 0) {
        double total = lds[0] + lds[1] + lds[2] + lds[3];
        const double LOG_2PI = 1.8378770664093454835606594728112;
        double c = n_obs * (16.0 * LOG_2PI + 0.5 * logdet_posterior(sp_prior, sp_like));
        out[0] = (float)(c + 0.5 * total);
    }
}

extern "C" void kernel_launch(void* const* d_in, const int* in_sizes, int n_in,
                              void* d_out, int out_size, void* d_ws, size_t ws_size,
                              hipStream_t stream) {
    const vfloat4* obs4   = (const vfloat4*)d_in[0];
    const float* mu_like  = (const float*)d_in[1];
    const float* pose     = (const float*)d_in[2];
    const float* sp_prior = (const float*)d_in[3];
    const float* sp_like  = (const float*)d_in[4];
    float* out = (float*)d_out;
    double* partials = (double*)d_ws;

    int n4 = in_sizes[0] / 4;                    // 8,388,608 float4s
    double n_obs = (double)(in_sizes[0] / 16);   // 2,000,000

    void* args[] = { (void*)&obs4, (void*)&mu_like, (void*)&pose,
                     (void*)&sp_prior, (void*)&sp_like,
                     (void*)&partials, (void*)&out, (void*)&n4, (void*)&n_obs };

    hipError_t err = hipLaunchCooperativeKernel(
        (const void*)fused_quad_kernel, dim3(NBLOCKS), dim3(NTHREADS),
        args, 0, stream);

    if (err != hipSuccess) {
        // capture-safe fallback: original two-dispatch pipeline
        quad_stream_kernel<<<NBLOCKS, NTHREADS, 0, stream>>>(
            obs4, mu_like, pose, sp_prior, sp_like, partials, n4);
        finalize_kernel<<<1, NTHREADS, 0, stream>>>(
            partials, sp_prior, sp_like, out, NBLOCKS, n_obs);
    }
}

// Round 2
// 189.765 us; speedup vs baseline: 1.8636x; 1.8636x over previous
//
#include <hip/hip_runtime.h>
#include <math.h>

#define EPS_COV 1e-6f
// 1953 blocks x 256 = 499,968 threads: n4 = 8,000,000 float4s ->
// exactly TWO full 8-deep batches per thread (2*8*499,968 = 7,999,488),
// 512-element scalar tail. Round-0's 2048 blocks left ~7 of 15.26
// elements/thread in the 1-deep tail loop (half the stream at MLP=1).
#define NBLOCKS 1953
#define NTHREADS 256

typedef float vfloat4 __attribute__((ext_vector_type(4)));  // nt-load-compatible

// ws layout: double partials[NBLOCKS] @ offset 0 (plain stores, reduced by finalize).

// Per-thread posterior params for row-quarter q: blocks n=2q and n=2q+1 ONLY
// (computing all 8 and discarding 6 wastes ~4x the divides/VALU).
// Arithmetic per block is expression-for-expression identical to the
// original, so numerics are unchanged.
__device__ __forceinline__ void setup_params(
    const float* __restrict__ mu_like, const float* __restrict__ pose,
    const float* __restrict__ sp_prior, const float* __restrict__ sp_like, int q,
    float& m0, float& m1, float& m2, float& m3,
    float& a0, float& b0, float& c0,
    float& a1, float& b1, float& c1)
{
    float cx = 0.f, cy = 0.f;
    #pragma unroll
    for (int i = 0; i < 8; ++i) { cx += mu_like[2*i]; cy += mu_like[2*i+1]; }
    cx *= 0.125f; cy *= 0.125f;
    const float ct = cosf(pose[2]), st = sinf(pose[2]);
    const float tx = pose[0], ty = pose[1];

    #pragma unroll
    for (int k = 0; k < 2; ++k) {
        const int n = 2*q + k;
        float px = mu_like[2*n]   - cx;
        float py = mu_like[2*n+1] - cy;
        float mp0 = ct*px - st*py + tx;
        float mp1 = st*px + ct*py + ty;

        const float* p = sp_prior + 4*n;
        float s00 = p[0]*p[0] + p[1]*p[1] + EPS_COV;
        float s01 = p[0]*p[2] + p[1]*p[3];
        float s11 = p[2]*p[2] + p[3]*p[3] + EPS_COV;
        float det = s00*s11 - s01*s01;
        float Pp00 =  s11/det, Pp01 = -s01/det, Pp11 = s00/det;

        const float* l = sp_like + 4*n;
        float t00 = l[0]*l[0] + l[1]*l[1] + EPS_COV;
        float t01 = l[0]*l[2] + l[1]*l[3];
        float t11 = l[2]*l[2] + l[3]*l[3] + EPS_COV;
        float dl = t00*t11 - t01*t01;
        float Pl00 =  t11/dl, Pl01 = -t01/dl, Pl11 = t00/dl;

        float Q00 = Pp00 + Pl00, Q01 = Pp01 + Pl01, Q11 = Pp11 + Pl11;
        float dq = Q00*Q11 - Q01*Q01;
        float S00 = Q11/dq, S01 = -Q01/dq, S11v = Q00/dq;

        float ml0 = mu_like[2*n], ml1 = mu_like[2*n+1];
        float v0 = Pp00*mp0 + Pp01*mp1 + Pl00*ml0 + Pl01*ml1;
        float v1 = Pp01*mp0 + Pp11*mp1 + Pl01*ml0 + Pl11*ml1;
        float mpostx = S00*v0 + S01*v1;
        float mposty = S01*v0 + S11v*v1;

        if (k == 0) { m0 = mpostx; m1 = mposty; a0 = S00; b0 = 2.f*S01; c0 = S11v; }
        else        { m2 = mpostx; m3 = mposty; a1 = S00; b1 = 2.f*S01; c1 = S11v; }
    }
}

__device__ __forceinline__ double logdet_posterior(
    const float* __restrict__ sp_prior, const float* __restrict__ sp_like)
{
    double logdet = 0.0;
    for (int n = 0; n < 8; ++n) {
        const float* p = sp_prior + 4*n;
        double s00 = (double)p[0]*p[0] + (double)p[1]*p[1] + 1e-6;
        double s01 = (double)p[0]*p[2] + (double)p[1]*p[3];
        double s11 = (double)p[2]*p[2] + (double)p[3]*p[3] + 1e-6;
        double det = s00*s11 - s01*s01;
        double Pp00 = s11/det, Pp01 = -s01/det, Pp11 = s00/det;
        const float* l = sp_like + 4*n;
        double t00 = (double)l[0]*l[0] + (double)l[1]*l[1] + 1e-6;
        double t01 = (double)l[0]*l[2] + (double)l[1]*l[3];
        double t11 = (double)l[2]*l[2] + (double)l[3]*l[3] + 1e-6;
        double dl = t00*t11 - t01*t01;
        double Pl00 = t11/dl, Pl01 = -t01/dl, Pl11 = t00/dl;
        double Q00 = Pp00 + Pl00, Q01 = Pp01 + Pl01, Q11 = Pp11 + Pl11;
        logdet += log(Q00*Q11 - Q01*Q01);
    }
    return logdet;
}

__global__ __launch_bounds__(NTHREADS) void quad_stream_kernel(
    const vfloat4* __restrict__ obs4,
    const float*  __restrict__ mu_like,
    const float*  __restrict__ pose,
    const float*  __restrict__ sp_prior,
    const float*  __restrict__ sp_like,
    double*       __restrict__ partials,
    int n4)
{
    const int tid    = blockIdx.x * blockDim.x + threadIdx.x;
    const int stride = gridDim.x * blockDim.x;   // multiple of 4 -> q loop-invariant
    const int q = tid & 3;                       // which float4-quarter of the row

    float m0, m1, m2, m3, a0, b0, c0, a1, b1, c1;
    setup_params(mu_like, pose, sp_prior, sp_like, q,
                 m0, m1, m2, m3, a0, b0, c0, a1, b1, c1);

    // ---- streaming quad-form accumulation, NON-TEMPORAL loads ----
    float acc0 = 0.f, acc1 = 0.f;
    int i = tid;
    while (i + 7*stride < n4) {                  // exactly 2 iterations at 1953x256
        vfloat4 v[8];
        #pragma unroll
        for (int j = 0; j < 8; ++j)
            v[j] = __builtin_nontemporal_load(&obs4[i + j*stride]);
        #pragma unroll
        for (int j = 0; j < 8; ++j) {
            float d0 = v[j].x - m0, d1 = v[j].y - m1;
            float d2 = v[j].z - m2, d3 = v[j].w - m3;
            float t = a0*d0*d0 + b0*(d0*d1) + c0*d1*d1
                    + a1*d2*d2 + b1*(d2*d3) + c1*d3*d3;
            if (j & 1) acc1 += t; else acc0 += t;
        }
        i += 8*stride;
    }
    for (; i < n4; i += stride) {                // 512 threads do ONE iteration
        vfloat4 v = __builtin_nontemporal_load(&obs4[i]);
        float d0 = v.x - m0, d1 = v.y - m1;
        float d2 = v.z - m2, d3 = v.w - m3;
        acc0 += a0*d0*d0 + b0*(d0*d1) + c0*d1*d1
              + a1*d2*d2 + b1*(d2*d3) + c1*d3*d3;
    }

    double accd = (double)acc0 + (double)acc1;

    #pragma unroll
    for (int off = 32; off > 0; off >>= 1)
        accd += __shfl_down(accd, off, 64);

    __shared__ double lds[4];
    const int wave = threadIdx.x >> 6;
    if ((threadIdx.x & 63) == 0) lds[wave] = accd;
    __syncthreads();
    if (threadIdx.x == 0)
        partials[blockIdx.x] = lds[0] + lds[1] + lds[2] + lds[3];
}

__global__ __launch_bounds__(NTHREADS) void finalize_kernel(
    const double* __restrict__ partials,
    const float*  __restrict__ sp_prior,
    const float*  __restrict__ sp_like,
    float*        __restrict__ out,
    int nblocks, double n_obs)
{
    double s = 0.0;
    for (int i = threadIdx.x; i < nblocks; i += NTHREADS) s += partials[i];
    #pragma unroll
    for (int off = 32; off > 0; off >>= 1)
        s += __shfl_down(s, off, 64);
    __shared__ double lds[4];
    const int wave = threadIdx.x >> 6;
    if ((threadIdx.x & 63) == 0) lds[wave] = s;
    __syncthreads();

    if (threadIdx.x == 0) {
        double total = lds[0] + lds[1] + lds[2] + lds[3];
        const double LOG_2PI = 1.8378770664093454835606594728112;
        double c = n_obs * (16.0 * LOG_2PI + 0.5 * logdet_posterior(sp_prior, sp_like));
        out[0] = (float)(c + 0.5 * total);
    }
}

extern "C" void kernel_launch(void* const* d_in, const int* in_sizes, int n_in,
                              void* d_out, int out_size, void* d_ws, size_t ws_size,
                              hipStream_t stream) {
    const float* obs      = (const float*)d_in[0];
    const float* mu_like  = (const float*)d_in[1];
    const float* pose     = (const float*)d_in[2];
    const float* sp_prior = (const float*)d_in[3];
    const float* sp_like  = (const float*)d_in[4];
    float* out = (float*)d_out;

    double* partials = (double*)d_ws;

    const int n_elems  = in_sizes[0];        // 32,000,000
    const int n4       = n_elems / 4;        // 8,000,000 float4s
    const double n_obs = (double)(n_elems / 16);

    quad_stream_kernel<<<NBLOCKS, NTHREADS, 0, stream>>>(
        (const vfloat4*)obs, mu_like, pose, sp_prior, sp_like, partials, n4);

    finalize_kernel<<<1, NTHREADS, 0, stream>>>(partials, sp_prior, sp_like, out, NBLOCKS, n_obs);
}

// Round 3
// 188.051 us; speedup vs baseline: 1.8805x; 1.0091x over previous
//
#include <hip/hip_runtime.h>
#include <math.h>

#define EPS_COV 1e-6f
// 2048 blocks x 256 = 524,288 threads = 8192 waves / 1024 SIMDs = EXACTLY
// 8 waves/SIMD (perfect residency + balance; VGPR=40 <= 64 so 8 waves/SIMD fits).
// Work decomposition over n4 = 8,000,000 float4s with stride 524,288:
//   tid < 135,680            : two 8-deep batches            (16 elems)
//   135,680 <= tid < 524,288 : 8-deep + 4-deep + 2-deep + 1  (15 elems)
// Total = 135,680*16 + 388,608*15 = 8,000,000 exactly. Per-CU imbalance <1%
// (round-robin block->CU gives each CU 122-123 element-units).
// Round-2's 1953-block grid had 7.63 waves/SIMD -> ~5% SIMD-count imbalance.
#define NBLOCKS 2048
#define NTHREADS 256

typedef float vfloat4 __attribute__((ext_vector_type(4)));  // nt-load-compatible

// ws layout: double partials[NBLOCKS] @ offset 0 (plain stores, reduced by finalize).

// Per-thread posterior params for row-quarter q: blocks n=2q and n=2q+1 ONLY.
// Arithmetic per block is expression-for-expression identical to the original.
__device__ __forceinline__ void setup_params(
    const float* __restrict__ mu_like, const float* __restrict__ pose,
    const float* __restrict__ sp_prior, const float* __restrict__ sp_like, int q,
    float& m0, float& m1, float& m2, float& m3,
    float& a0, float& b0, float& c0,
    float& a1, float& b1, float& c1)
{
    float cx = 0.f, cy = 0.f;
    #pragma unroll
    for (int i = 0; i < 8; ++i) { cx += mu_like[2*i]; cy += mu_like[2*i+1]; }
    cx *= 0.125f; cy *= 0.125f;
    const float ct = cosf(pose[2]), st = sinf(pose[2]);
    const float tx = pose[0], ty = pose[1];

    #pragma unroll
    for (int k = 0; k < 2; ++k) {
        const int n = 2*q + k;
        float px = mu_like[2*n]   - cx;
        float py = mu_like[2*n+1] - cy;
        float mp0 = ct*px - st*py + tx;
        float mp1 = st*px + ct*py + ty;

        const float* p = sp_prior + 4*n;
        float s00 = p[0]*p[0] + p[1]*p[1] + EPS_COV;
        float s01 = p[0]*p[2] + p[1]*p[3];
        float s11 = p[2]*p[2] + p[3]*p[3] + EPS_COV;
        float det = s00*s11 - s01*s01;
        float Pp00 =  s11/det, Pp01 = -s01/det, Pp11 = s00/det;

        const float* l = sp_like + 4*n;
        float t00 = l[0]*l[0] + l[1]*l[1] + EPS_COV;
        float t01 = l[0]*l[2] + l[1]*l[3];
        float t11 = l[2]*l[2] + l[3]*l[3] + EPS_COV;
        float dl = t00*t11 - t01*t01;
        float Pl00 =  t11/dl, Pl01 = -t01/dl, Pl11 = t00/dl;

        float Q00 = Pp00 + Pl00, Q01 = Pp01 + Pl01, Q11 = Pp11 + Pl11;
        float dq = Q00*Q11 - Q01*Q01;
        float S00 = Q11/dq, S01 = -Q01/dq, S11v = Q00/dq;

        float ml0 = mu_like[2*n], ml1 = mu_like[2*n+1];
        float v0 = Pp00*mp0 + Pp01*mp1 + Pl00*ml0 + Pl01*ml1;
        float v1 = Pp01*mp0 + Pp11*mp1 + Pl01*ml0 + Pl11*ml1;
        float mpostx = S00*v0 + S01*v1;
        float mposty = S01*v0 + S11v*v1;

        if (k == 0) { m0 = mpostx; m1 = mposty; a0 = S00; b0 = 2.f*S01; c0 = S11v; }
        else        { m2 = mpostx; m3 = mposty; a1 = S00; b1 = 2.f*S01; c1 = S11v; }
    }
}

__device__ __forceinline__ double logdet_posterior(
    const float* __restrict__ sp_prior, const float* __restrict__ sp_like)
{
    double logdet = 0.0;
    for (int n = 0; n < 8; ++n) {
        const float* p = sp_prior + 4*n;
        double s00 = (double)p[0]*p[0] + (double)p[1]*p[1] + 1e-6;
        double s01 = (double)p[0]*p[2] + (double)p[1]*p[3];
        double s11 = (double)p[2]*p[2] + (double)p[3]*p[3] + 1e-6;
        double det = s00*s11 - s01*s01;
        double Pp00 = s11/det, Pp01 = -s01/det, Pp11 = s00/det;
        const float* l = sp_like + 4*n;
        double t00 = (double)l[0]*l[0] + (double)l[1]*l[1] + 1e-6;
        double t01 = (double)l[0]*l[2] + (double)l[1]*l[3];
        double t11 = (double)l[2]*l[2] + (double)l[3]*l[3] + 1e-6;
        double dl = t00*t11 - t01*t01;
        double Pl00 = t11/dl, Pl01 = -t01/dl, Pl11 = t00/dl;
        double Q00 = Pp00 + Pl00, Q01 = Pp01 + Pl01, Q11 = Pp11 + Pl11;
        logdet += log(Q00*Q11 - Q01*Q01);
    }
    return logdet;
}

// Shared quad-form body for one loaded float4.
#define QUAD_ACC(v, acc)                                            \
    do {                                                            \
        float d0 = (v).x - m0, d1 = (v).y - m1;                     \
        float d2 = (v).z - m2, d3 = (v).w - m3;                     \
        (acc) += a0*d0*d0 + b0*(d0*d1) + c0*d1*d1                   \
               + a1*d2*d2 + b1*(d2*d3) + c1*d3*d3;                  \
    } while (0)

__global__ __launch_bounds__(NTHREADS) void quad_stream_kernel(
    const vfloat4* __restrict__ obs4,
    const float*  __restrict__ mu_like,
    const float*  __restrict__ pose,
    const float*  __restrict__ sp_prior,
    const float*  __restrict__ sp_like,
    double*       __restrict__ partials,
    int n4)
{
    const int tid    = blockIdx.x * blockDim.x + threadIdx.x;
    const int stride = gridDim.x * blockDim.x;   // multiple of 4 -> q loop-invariant
    const int q = tid & 3;                       // which float4-quarter of the row

    float m0, m1, m2, m3, a0, b0, c0, a1, b1, c1;
    setup_params(mu_like, pose, sp_prior, sp_like, q,
                 m0, m1, m2, m3, a0, b0, c0, a1, b1, c1);

    // ---- streaming quad-form accumulation, NON-TEMPORAL loads ----
    // Binary depth decomposition: 8-deep bulk, then 4/2/1 shrinking batches.
    // Keeps MLP high for the whole stream with no scalar-tail cliff.
    float acc0 = 0.f, acc1 = 0.f;
    int i = tid;

    while (i + 7*stride < n4) {
        vfloat4 v[8];
        #pragma unroll
        for (int j = 0; j < 8; ++j)
            v[j] = __builtin_nontemporal_load(&obs4[i + j*stride]);
        #pragma unroll
        for (int j = 0; j < 8; ++j) {
            if (j & 1) QUAD_ACC(v[j], acc1); else QUAD_ACC(v[j], acc0);
        }
        i += 8*stride;
    }
    if (i + 3*stride < n4) {
        vfloat4 v[4];
        #pragma unroll
        for (int j = 0; j < 4; ++j)
            v[j] = __builtin_nontemporal_load(&obs4[i + j*stride]);
        #pragma unroll
        for (int j = 0; j < 4; ++j) {
            if (j & 1) QUAD_ACC(v[j], acc1); else QUAD_ACC(v[j], acc0);
        }
        i += 4*stride;
    }
    if (i + stride < n4) {
        vfloat4 v0 = __builtin_nontemporal_load(&obs4[i]);
        vfloat4 v1 = __builtin_nontemporal_load(&obs4[i + stride]);
        QUAD_ACC(v0, acc0);
        QUAD_ACC(v1, acc1);
        i += 2*stride;
    }
    while (i < n4) {
        vfloat4 v = __builtin_nontemporal_load(&obs4[i]);
        QUAD_ACC(v, acc0);
        i += stride;
    }

    double accd = (double)acc0 + (double)acc1;

    #pragma unroll
    for (int off = 32; off > 0; off >>= 1)
        accd += __shfl_down(accd, off, 64);

    __shared__ double lds[4];
    const int wave = threadIdx.x >> 6;
    if ((threadIdx.x & 63) == 0) lds[wave] = accd;
    __syncthreads();
    if (threadIdx.x == 0)
        partials[blockIdx.x] = lds[0] + lds[1] + lds[2] + lds[3];
}

__global__ __launch_bounds__(NTHREADS) void finalize_kernel(
    const double* __restrict__ partials,
    const float*  __restrict__ sp_prior,
    const float*  __restrict__ sp_like,
    float*        __restrict__ out,
    int nblocks, double n_obs)
{
    double s = 0.0;
    for (int i = threadIdx.x; i < nblocks; i += NTHREADS) s += partials[i];
    #pragma unroll
    for (int off = 32; off > 0; off >>= 1)
        s += __shfl_down(s, off, 64);
    __shared__ double lds[4];
    const int wave = threadIdx.x >> 6;
    if ((threadIdx.x & 63) == 0) lds[wave] = s;
    __syncthreads();

    if (threadIdx.x == 0) {
        double total = lds[0] + lds[1] + lds[2] + lds[3];
        const double LOG_2PI = 1.8378770664093454835606594728112;
        double c = n_obs * (16.0 * LOG_2PI + 0.5 * logdet_posterior(sp_prior, sp_like));
        out[0] = (float)(c + 0.5 * total);
    }
}

extern "C" void kernel_launch(void* const* d_in, const int* in_sizes, int n_in,
                              void* d_out, int out_size, void* d_ws, size_t ws_size,
                              hipStream_t stream) {
    const float* obs      = (const float*)d_in[0];
    const float* mu_like  = (const float*)d_in[1];
    const float* pose     = (const float*)d_in[2];
    const float* sp_prior = (const float*)d_in[3];
    const float* sp_like  = (const float*)d_in[4];
    float* out = (float*)d_out;

    double* partials = (double*)d_ws;

    const int n_elems  = in_sizes[0];        // 32,000,000
    const int n4       = n_elems / 4;        // 8,000,000 float4s
    const double n_obs = (double)(n_elems / 16);

    quad_stream_kernel<<<NBLOCKS, NTHREADS, 0, stream>>>(
        (const vfloat4*)obs, mu_like, pose, sp_prior, sp_like, partials, n4);

    finalize_kernel<<<1, NTHREADS, 0, stream>>>(partials, sp_prior, sp_like, out, NBLOCKS, n_obs);
}